// Round 4
// baseline (234.803 us; speedup 1.0000x reference)
//
#include <hip/hip_runtime.h>

// ---------------------------------------------------------------------------
// FISTA sparse coding, independent-wave version, R2-exact numerics:
//   L = ||A||_F^2 ; M = A A^T / L (128x128 bf16) ; B = X A^T / L
//   Each wave (block=64) owns 16 samples and ALL 128 codes:
//     - M entirely in VGPRs (128 regs), loaded once after the prologue
//     - state zr/xr/Bn in f32 registers (bf16 ONLY in the LDS/MFMA copy of z)
//     - wave-private 4KB LDS z scratch; zero barriers (in-wave DS ordering)
//     - last iteration peeled: x written in f32 directly
// ---------------------------------------------------------------------------

typedef __attribute__((ext_vector_type(8))) __bf16 bf16x8;
typedef __attribute__((ext_vector_type(4))) float f32x4;
typedef __attribute__((ext_vector_type(4))) unsigned short u16x4;
typedef __attribute__((ext_vector_type(4))) unsigned int u32x4;

#define NITER 80

__device__ __forceinline__ unsigned short f2bf(float f) {
  unsigned int u = __builtin_bit_cast(unsigned int, f);
  u += 0x7FFFu + ((u >> 16) & 1u);   // RNE
  return (unsigned short)(u >> 16);
}
__device__ __forceinline__ float med3(float a, float b, float c) {
  float r;
  asm("v_med3_f32 %0, %1, %2, %3" : "=v"(r) : "v"(a), "v"(b), "v"(c));
  return r;
}

// ---- kernel 1: A(f32) -> A_bf16, plus per-block partial sums of A^2 --------
__global__ __launch_bounds__(256) void prep_a(const float* __restrict__ A,
                                              unsigned short* __restrict__ Abf,
                                              float* __restrict__ partials) {
  int tid = threadIdx.x;
  int idx = (blockIdx.x * 256 + tid) * 4;          // 128 blocks * 1024 f32
  float4 v = *(const float4*)(A + idx);
  u16x4 o;
  o[0] = f2bf(v.x); o[1] = f2bf(v.y); o[2] = f2bf(v.z); o[3] = f2bf(v.w);
  *(u16x4*)(Abf + idx) = o;
  float p = v.x * v.x + v.y * v.y + v.z * v.z + v.w * v.w;
#pragma unroll
  for (int m = 32; m >= 1; m >>= 1) p += __shfl_xor(p, m, 64);
  __shared__ float red[4];
  if ((tid & 63) == 0) red[tid >> 6] = p;
  __syncthreads();
  if (tid == 0) partials[blockIdx.x] = red[0] + red[1] + red[2] + red[3];
}

// ---- kernel 2: M_bf16[k][j] = bf16(dot(A_k, A_j)/L); also store L ----------
__global__ __launch_bounds__(256) void prep_m(const float* __restrict__ A,
                                              const float* __restrict__ partials,
                                              float* __restrict__ Lout,
                                              unsigned short* __restrict__ Mb) {
  int tid = threadIdx.x;
  int k = blockIdx.x;
  int w = tid >> 6, l = tid & 63;
  __shared__ float ak[1024];
  *(float4*)(ak + tid * 4) = *(const float4*)(A + k * 1024 + tid * 4);
  float L = 0.f;
#pragma unroll 1
  for (int i = 0; i < 128; ++i) L += partials[i];  // fixed order: deterministic
  float invL = 1.0f / L;
  if (k == 0 && tid == 0) Lout[0] = L;
  __syncthreads();
#pragma unroll 1
  for (int jj = 0; jj < 32; ++jj) {
    int j = w * 32 + jj;
    const float* aj = A + j * 1024;
    float p = 0.f;
#pragma unroll
    for (int q = 0; q < 4; ++q) {
      float4 x = *(const float4*)(aj + q * 256 + l * 4);
      float4 y = *(const float4*)(ak + q * 256 + l * 4);
      p += x.x * y.x + x.y * y.y + x.z * y.z + x.w * y.w;
    }
#pragma unroll
    for (int m = 32; m >= 1; m >>= 1) p += __shfl_xor(p, m, 64);
    if (l == 0) Mb[k * 128 + j] = f2bf(p * invL);
  }
}

// ---- kernel 3: FISTA, one wave = 16 samples x 128 codes, zero barriers -----
// lane l: li=l&15 (sample), g=l>>4.
//   mfr[t][m] : A-frag of M, rows 16t+li, k=32m+8g..+8      (t<8, m<4)
//   zf[m]     : B-frag, col(sample)=li, k(code)=32m+8g..+8
//   D[t]      : codes 16t+4g+r (r<4), sample li
// LDS zs[16 samples][128 codes] bf16, 16B chunks XOR-swizzled by sample:
// ushort = li*128 + ((chunk ^ li)*8) + within.
__global__ __launch_bounds__(64, 2) void fista(const float* __restrict__ X,
                                               const unsigned short* __restrict__ Abf,
                                               const unsigned short* __restrict__ Mb,
                                               const float* __restrict__ Lptr,
                                               float* __restrict__ out) {
  int l = threadIdx.x;
  int li = l & 15, g = l >> 4;
  int s0 = blockIdx.x * 16;

  __shared__ __align__(16) unsigned short zls[2048];  // 4 KB, wave-private

  float L = Lptr[0];
  float invL = 1.0f / L;
  float thr = 0.2f / L;
  float nthr = -thr;

  // zero the scratch (z0 = 0); single wave -> no barrier
#pragma unroll
  for (int i = 0; i < 4; ++i)
    *(u32x4*)(zls + l * 32 + i * 8) = u32x4{0u, 0u, 0u, 0u};

  // ---- prologue: acc[t] = Abf . X^T (K=1024), X read direct from global ----
  f32x4 acc[8];
#pragma unroll
  for (int t = 0; t < 8; ++t) acc[t] = f32x4{0.f, 0.f, 0.f, 0.f};

  const float* xrow = X + (size_t)(s0 + li) * 1024 + 8 * g;
  const unsigned short* arow = Abf + (size_t)li * 1024 + 8 * g;
#pragma unroll 2
  for (int ks = 0; ks < 32; ++ks) {
    float4 v0 = *(const float4*)(xrow + ks * 32);
    float4 v1 = *(const float4*)(xrow + ks * 32 + 4);
    bf16x8 xf;
    xf[0] = (__bf16)v0.x; xf[1] = (__bf16)v0.y; xf[2] = (__bf16)v0.z; xf[3] = (__bf16)v0.w;
    xf[4] = (__bf16)v1.x; xf[5] = (__bf16)v1.y; xf[6] = (__bf16)v1.z; xf[7] = (__bf16)v1.w;
#pragma unroll
    for (int t = 0; t < 8; ++t) {
      bf16x8 af = *(const bf16x8*)(arow + (size_t)t * 16384 + ks * 32);
      acc[t] = __builtin_amdgcn_mfma_f32_16x16x32_bf16(af, xf, acc[t], 0, 0, 0);
    }
  }
  f32x4 Bn[8];
#pragma unroll
  for (int t = 0; t < 8; ++t) Bn[t] = -(acc[t] * invL);   // Bn = -B

  // M fragments pinned in registers (128 VGPRs), loaded after prologue
  bf16x8 mfr[8][4];
#pragma unroll
  for (int t = 0; t < 8; ++t)
#pragma unroll
    for (int m = 0; m < 4; ++m)
      mfr[t][m] = *(const bf16x8*)(Mb + (16 * t + li) * 128 + 32 * m + 8 * g);

  // f32 state in registers (R2-exact numerics)
  f32x4 zr[8], xr[8];
#pragma unroll
  for (int t = 0; t < 8; ++t) {
    zr[t] = f32x4{0.f, 0.f, 0.f, 0.f};
    xr[t] = f32x4{0.f, 0.f, 0.f, 0.f};
  }

  // LDS offsets (ushort units)
  int roff[4], woff[8];
#pragma unroll
  for (int m = 0; m < 4; ++m) roff[m] = li * 128 + (((4 * m + g) ^ li) * 8);
#pragma unroll
  for (int t = 0; t < 8; ++t)
    woff[t] = li * 128 + (((2 * t + (g >> 1)) ^ li) * 8) + (g & 1) * 4;

  float tf = 1.0f;
#pragma unroll 1
  for (int it = 0; it < NITER - 1; ++it) {
    float tn = 0.5f * (1.0f + sqrtf(1.0f + 4.0f * tf * tf));
    float c = (tf - 1.0f) / tn;
    tf = tn;

    bf16x8 zf[4];
#pragma unroll
    for (int m = 0; m < 4; ++m) zf[m] = *(const bf16x8*)(zls + roff[m]);

#pragma unroll
    for (int t = 0; t < 8; ++t) {
      f32x4 d = Bn[t] - zr[t];                 // C = -B - z
      d = __builtin_amdgcn_mfma_f32_16x16x32_bf16(mfr[t][0], zf[0], d, 0, 0, 0);
      d = __builtin_amdgcn_mfma_f32_16x16x32_bf16(mfr[t][1], zf[1], d, 0, 0, 0);
      d = __builtin_amdgcn_mfma_f32_16x16x32_bf16(mfr[t][2], zf[2], d, 0, 0, 0);
      d = __builtin_amdgcn_mfma_f32_16x16x32_bf16(mfr[t][3], zf[3], d, 0, 0, 0);
      // D = zM - z - B  =>  zpre = -D ;  soft(-d,thr) = clamp(d,-thr,thr) - d
      f32x4 xn, zm;
#pragma unroll
      for (int r = 0; r < 4; ++r) {
        float dd = d[r];
        float cl = med3(dd, nthr, thr);
        float x1 = cl - dd;
        xn[r] = x1;
        zm[r] = x1 + c * (x1 - xr[t][r]);      // momentum
      }
      xr[t] = xn;
      zr[t] = zm;
      u16x4 pv;
      pv[0] = __builtin_bit_cast(unsigned short, (__bf16)zm[0]);
      pv[1] = __builtin_bit_cast(unsigned short, (__bf16)zm[1]);
      pv[2] = __builtin_bit_cast(unsigned short, (__bf16)zm[2]);
      pv[3] = __builtin_bit_cast(unsigned short, (__bf16)zm[3]);
      *(u16x4*)(zls + woff[t]) = pv;           // 8B ds_write_b64
    }
  }

  // ---- final (80th) step: compute x in f32, store directly ----
  {
    bf16x8 zf[4];
#pragma unroll
    for (int m = 0; m < 4; ++m) zf[m] = *(const bf16x8*)(zls + roff[m]);
#pragma unroll
    for (int t = 0; t < 8; ++t) {
      f32x4 d = Bn[t] - zr[t];
      d = __builtin_amdgcn_mfma_f32_16x16x32_bf16(mfr[t][0], zf[0], d, 0, 0, 0);
      d = __builtin_amdgcn_mfma_f32_16x16x32_bf16(mfr[t][1], zf[1], d, 0, 0, 0);
      d = __builtin_amdgcn_mfma_f32_16x16x32_bf16(mfr[t][2], zf[2], d, 0, 0, 0);
      d = __builtin_amdgcn_mfma_f32_16x16x32_bf16(mfr[t][3], zf[3], d, 0, 0, 0);
      f32x4 xn;
#pragma unroll
      for (int r = 0; r < 4; ++r) {
        float dd = d[r];
        xn[r] = med3(dd, nthr, thr) - dd;
      }
      *(f32x4*)(out + (size_t)(s0 + li) * 128 + 16 * t + 4 * g) = xn;
    }
  }
}

extern "C" void kernel_launch(void* const* d_in, const int* in_sizes, int n_in,
                              void* d_out, int out_size, void* d_ws, size_t ws_size,
                              hipStream_t stream) {
  const float* X = (const float*)d_in[0];          // 32768 x 1024 f32
  const float* A = (const float*)d_in[1];          // 128 x 1024 f32
  float* out = (float*)d_out;                      // 32768 x 128 f32

  float* partials      = (float*)d_ws;                                   // 128 f32
  float* Lout          = (float*)((char*)d_ws + 512);                    // 1 f32
  unsigned short* Abf  = (unsigned short*)((char*)d_ws + 528);           // 256 KB
  unsigned short* Mb   = (unsigned short*)((char*)d_ws + 528 + 262144);  // 32 KB

  prep_a<<<128, 256, 0, stream>>>(A, Abf, partials);
  prep_m<<<128, 256, 0, stream>>>(A, partials, Lout, Mb);
  fista<<<2048, 64, 0, stream>>>(X, Abf, Mb, Lout, out);
}

// Round 5
// 201.149 us; speedup vs baseline: 1.1673x; 1.1673x over previous
//
#include <hip/hip_runtime.h>

// ---------------------------------------------------------------------------
// FISTA sparse coding:
//   L = ||A||_F^2 ; M = A A^T / L (128x128 bf16) ; B = X A^T / L
//   Block = 256 threads (4 waves) owns 16 samples; wave w owns codes
//   [32w, 32w+32).  Register plan (~100 VGPR, cap 128 via launch_bounds):
//     mfr[2][4]=32, Bn/zr/xr=24, zf=16, temps.
//   z (16 samples x 128 codes, bf16) in LDS, double-buffered, 1 barrier/iter.
//   State zr/xr/Bn in f32 registers (bf16 only in the LDS/MFMA copy of z).
//   Last iteration peeled: x computed in f32, stored directly.
// ---------------------------------------------------------------------------

typedef __attribute__((ext_vector_type(8))) __bf16 bf16x8;
typedef __attribute__((ext_vector_type(4))) float f32x4;
typedef __attribute__((ext_vector_type(4))) unsigned short u16x4;
typedef __attribute__((ext_vector_type(4))) unsigned int u32x4;

#define NITER 80

__device__ __forceinline__ unsigned short f2bf(float f) {
  unsigned int u = __builtin_bit_cast(unsigned int, f);
  u += 0x7FFFu + ((u >> 16) & 1u);   // RNE
  return (unsigned short)(u >> 16);
}
__device__ __forceinline__ float med3(float a, float b, float c) {
  float r;
  asm("v_med3_f32 %0, %1, %2, %3" : "=v"(r) : "v"(a), "v"(b), "v"(c));
  return r;
}

// ---- kernel 1: A(f32) -> A_bf16, plus per-block partial sums of A^2 --------
__global__ __launch_bounds__(256) void prep_a(const float* __restrict__ A,
                                              unsigned short* __restrict__ Abf,
                                              float* __restrict__ partials) {
  int tid = threadIdx.x;
  int idx = (blockIdx.x * 256 + tid) * 4;          // 128 blocks * 1024 f32
  float4 v = *(const float4*)(A + idx);
  u16x4 o;
  o[0] = f2bf(v.x); o[1] = f2bf(v.y); o[2] = f2bf(v.z); o[3] = f2bf(v.w);
  *(u16x4*)(Abf + idx) = o;
  float p = v.x * v.x + v.y * v.y + v.z * v.z + v.w * v.w;
#pragma unroll
  for (int m = 32; m >= 1; m >>= 1) p += __shfl_xor(p, m, 64);
  __shared__ float red[4];
  if ((tid & 63) == 0) red[tid >> 6] = p;
  __syncthreads();
  if (tid == 0) partials[blockIdx.x] = red[0] + red[1] + red[2] + red[3];
}

// ---- kernel 2: M_bf16[k][j] = bf16(dot(A_k, A_j)/L); also store L ----------
__global__ __launch_bounds__(256) void prep_m(const float* __restrict__ A,
                                              const float* __restrict__ partials,
                                              float* __restrict__ Lout,
                                              unsigned short* __restrict__ Mb) {
  int tid = threadIdx.x;
  int k = blockIdx.x;
  int w = tid >> 6, l = tid & 63;
  __shared__ float ak[1024];
  *(float4*)(ak + tid * 4) = *(const float4*)(A + k * 1024 + tid * 4);
  float L = 0.f;
#pragma unroll 1
  for (int i = 0; i < 128; ++i) L += partials[i];  // fixed order: deterministic
  float invL = 1.0f / L;
  if (k == 0 && tid == 0) Lout[0] = L;
  __syncthreads();
#pragma unroll 1
  for (int jj = 0; jj < 32; ++jj) {
    int j = w * 32 + jj;
    const float* aj = A + j * 1024;
    float p = 0.f;
#pragma unroll
    for (int q = 0; q < 4; ++q) {
      float4 x = *(const float4*)(aj + q * 256 + l * 4);
      float4 y = *(const float4*)(ak + q * 256 + l * 4);
      p += x.x * y.x + x.y * y.y + x.z * y.z + x.w * y.w;
    }
#pragma unroll
    for (int m = 32; m >= 1; m >>= 1) p += __shfl_xor(p, m, 64);
    if (l == 0) Mb[k * 128 + j] = f2bf(p * invL);
  }
}

// ---- kernel 3: FISTA, block = 4 waves x 16 samples; wave w: codes 32w.. ----
// lane l: li=l&15 (sample), g=l>>4.
//   mfr[t][m] : A-frag of M, rows 32w+16t+li, k=32m+8g..+8   (t<2, m<4)
//   zf[m]     : B-frag, col(sample)=li, k(code)=32m+8g..+8   (all 128 codes)
//   D[t]      : codes 32w+16t+4g+r (r<4), sample li
// LDS z[16][128] bf16 double-buffered; 16B chunks XOR-swizzled by sample:
// ushort = li*128 + ((chunk ^ li)*8) + within.
__global__ __launch_bounds__(256, 4) void fista(const float* __restrict__ X,
                                                const unsigned short* __restrict__ Abf,
                                                const unsigned short* __restrict__ Mb,
                                                const float* __restrict__ Lptr,
                                                float* __restrict__ out) {
  int tid = threadIdx.x;
  int w = tid >> 6, l = tid & 63;
  int li = l & 15, g = l >> 4;
  int s0 = blockIdx.x * 16;

  __shared__ __align__(16) unsigned short zls[2 * 2048];  // 8 KB double-buffer

  float L = Lptr[0];
  float invL = 1.0f / L;
  float thr = 0.2f / L;
  float nthr = -thr;

  // M fragments (32 VGPRs): rows 32w+16t+li
  bf16x8 mfr[2][4];
#pragma unroll
  for (int t = 0; t < 2; ++t)
#pragma unroll
    for (int m = 0; m < 4; ++m)
      mfr[t][m] = *(const bf16x8*)(Mb + (32 * w + 16 * t + li) * 128 + 32 * m + 8 * g);

  // ---- prologue: acc[t] = Abf_rows . X^T (K=1024), X direct from global ----
  f32x4 acc[2];
  acc[0] = f32x4{0.f, 0.f, 0.f, 0.f};
  acc[1] = f32x4{0.f, 0.f, 0.f, 0.f};

  const float* xrow = X + (size_t)(s0 + li) * 1024 + 8 * g;
  const unsigned short* arow = Abf + (size_t)(32 * w + li) * 1024 + 8 * g;
#pragma unroll 2
  for (int ks = 0; ks < 32; ++ks) {
    float4 v0 = *(const float4*)(xrow + ks * 32);
    float4 v1 = *(const float4*)(xrow + ks * 32 + 4);
    bf16x8 xf;
    xf[0] = (__bf16)v0.x; xf[1] = (__bf16)v0.y; xf[2] = (__bf16)v0.z; xf[3] = (__bf16)v0.w;
    xf[4] = (__bf16)v1.x; xf[5] = (__bf16)v1.y; xf[6] = (__bf16)v1.z; xf[7] = (__bf16)v1.w;
#pragma unroll
    for (int t = 0; t < 2; ++t) {
      bf16x8 af = *(const bf16x8*)(arow + (size_t)t * 16384 + ks * 32);
      acc[t] = __builtin_amdgcn_mfma_f32_16x16x32_bf16(af, xf, acc[t], 0, 0, 0);
    }
  }
  f32x4 Bn[2];
  Bn[0] = -(acc[0] * invL);                    // Bn = -B
  Bn[1] = -(acc[1] * invL);

  // f32 state in registers
  f32x4 zr[2], xr[2];
#pragma unroll
  for (int t = 0; t < 2; ++t) {
    zr[t] = f32x4{0.f, 0.f, 0.f, 0.f};
    xr[t] = f32x4{0.f, 0.f, 0.f, 0.f};
  }

  // zero z buffer 0 (z0 = 0): 4 KB over 256 threads = 16 B each
  *(u32x4*)(zls + tid * 8) = u32x4{0u, 0u, 0u, 0u};
  __syncthreads();

  // LDS offsets (ushort units)
  int roff[4], woff[2];
#pragma unroll
  for (int m = 0; m < 4; ++m) roff[m] = li * 128 + (((4 * m + g) ^ li) * 8);
#pragma unroll
  for (int t = 0; t < 2; ++t)
    woff[t] = li * 128 + (((4 * w + 2 * t + (g >> 1)) ^ li) * 8) + (g & 1) * 4;

  float tf = 1.0f;
#pragma unroll 1
  for (int it = 0; it < NITER - 1; ++it) {
    float tn = 0.5f * (1.0f + sqrtf(1.0f + 4.0f * tf * tf));
    float c = (tf - 1.0f) / tn;
    tf = tn;
    const unsigned short* rd = zls + (it & 1) * 2048;
    unsigned short* wr = zls + ((it + 1) & 1) * 2048;

    bf16x8 zf[4];
#pragma unroll
    for (int m = 0; m < 4; ++m) zf[m] = *(const bf16x8*)(rd + roff[m]);

#pragma unroll
    for (int t = 0; t < 2; ++t) {
      f32x4 d = Bn[t] - zr[t];                 // C = -B - z
      d = __builtin_amdgcn_mfma_f32_16x16x32_bf16(mfr[t][0], zf[0], d, 0, 0, 0);
      d = __builtin_amdgcn_mfma_f32_16x16x32_bf16(mfr[t][1], zf[1], d, 0, 0, 0);
      d = __builtin_amdgcn_mfma_f32_16x16x32_bf16(mfr[t][2], zf[2], d, 0, 0, 0);
      d = __builtin_amdgcn_mfma_f32_16x16x32_bf16(mfr[t][3], zf[3], d, 0, 0, 0);
      // D = zM - z - B  =>  zpre = -D ;  soft(-d,thr) = clamp(d,-thr,thr) - d
      f32x4 xn, zm;
#pragma unroll
      for (int r = 0; r < 4; ++r) {
        float dd = d[r];
        float cl = med3(dd, nthr, thr);
        float x1 = cl - dd;
        xn[r] = x1;
        zm[r] = x1 + c * (x1 - xr[t][r]);      // momentum
      }
      xr[t] = xn;
      zr[t] = zm;
      u16x4 pv;
      pv[0] = __builtin_bit_cast(unsigned short, (__bf16)zm[0]);
      pv[1] = __builtin_bit_cast(unsigned short, (__bf16)zm[1]);
      pv[2] = __builtin_bit_cast(unsigned short, (__bf16)zm[2]);
      pv[3] = __builtin_bit_cast(unsigned short, (__bf16)zm[3]);
      *(u16x4*)(wr + woff[t]) = pv;            // 8B ds_write_b64
    }
    __syncthreads();
  }

  // ---- final (80th) step: compute x in f32, store directly ----
  {
    const unsigned short* rd = zls + ((NITER - 1) & 1) * 2048;
    bf16x8 zf[4];
#pragma unroll
    for (int m = 0; m < 4; ++m) zf[m] = *(const bf16x8*)(rd + roff[m]);
#pragma unroll
    for (int t = 0; t < 2; ++t) {
      f32x4 d = Bn[t] - zr[t];
      d = __builtin_amdgcn_mfma_f32_16x16x32_bf16(mfr[t][0], zf[0], d, 0, 0, 0);
      d = __builtin_amdgcn_mfma_f32_16x16x32_bf16(mfr[t][1], zf[1], d, 0, 0, 0);
      d = __builtin_amdgcn_mfma_f32_16x16x32_bf16(mfr[t][2], zf[2], d, 0, 0, 0);
      d = __builtin_amdgcn_mfma_f32_16x16x32_bf16(mfr[t][3], zf[3], d, 0, 0, 0);
      f32x4 xn;
#pragma unroll
      for (int r = 0; r < 4; ++r) {
        float dd = d[r];
        xn[r] = med3(dd, nthr, thr) - dd;
      }
      *(f32x4*)(out + (size_t)(s0 + li) * 128 + 32 * w + 16 * t + 4 * g) = xn;
    }
  }
}

extern "C" void kernel_launch(void* const* d_in, const int* in_sizes, int n_in,
                              void* d_out, int out_size, void* d_ws, size_t ws_size,
                              hipStream_t stream) {
  const float* X = (const float*)d_in[0];          // 32768 x 1024 f32
  const float* A = (const float*)d_in[1];          // 128 x 1024 f32
  float* out = (float*)d_out;                      // 32768 x 128 f32

  float* partials      = (float*)d_ws;                                   // 128 f32
  float* Lout          = (float*)((char*)d_ws + 512);                    // 1 f32
  unsigned short* Abf  = (unsigned short*)((char*)d_ws + 528);           // 256 KB
  unsigned short* Mb   = (unsigned short*)((char*)d_ws + 528 + 262144);  // 32 KB

  prep_a<<<128, 256, 0, stream>>>(A, Abf, partials);
  prep_m<<<128, 256, 0, stream>>>(A, partials, Lout, Mb);
  fista<<<2048, 256, 0, stream>>>(X, Abf, Mb, Lout, out);
}

// Round 6
// 184.809 us; speedup vs baseline: 1.2705x; 1.0884x over previous
//
#include <hip/hip_runtime.h>

// ---------------------------------------------------------------------------
// FISTA sparse coding:
//   L = ||A||_F^2 ; M = A A^T / L (128x128 bf16) ; B = X A^T / L
//   Block = 256 threads (4 waves) owns 32 samples (2 groups of 16); wave w
//   owns codes [32w, 32w+32).  Negated register state (nz=-z, nx=-x) so the
//   whole per-element update runs on packed-f32 (VOP3P) + med3 + cvt_pk(-).
//   Momentum coefficients (-c_k, 1+c_k) precomputed in prep_m (kills the
//   per-iteration sqrt/div).  Iteration loop unrolled 2x for compile-time
//   LDS double-buffer offsets.  z bf16 in LDS, 1 barrier/iter.
// ---------------------------------------------------------------------------

typedef __attribute__((ext_vector_type(8))) __bf16 bf16x8;
typedef __attribute__((ext_vector_type(4))) float f32x4;
typedef __attribute__((ext_vector_type(2))) float f32x2;
typedef __attribute__((ext_vector_type(4))) unsigned short u16x4;
typedef __attribute__((ext_vector_type(2))) unsigned int u32x2;
typedef __attribute__((ext_vector_type(4))) unsigned int u32x4;

#define NITER 80

__device__ __forceinline__ unsigned short f2bf(float f) {
  unsigned int u = __builtin_bit_cast(unsigned int, f);
  u += 0x7FFFu + ((u >> 16) & 1u);   // RNE
  return (unsigned short)(u >> 16);
}
__device__ __forceinline__ float med3(float a, float b, float c) {
  float r;
  asm("v_med3_f32 %0, %1, %2, %3" : "=v"(r) : "v"(a), "v"(b), "v"(c));
  return r;
}
__device__ __forceinline__ f32x2 pk_add(f32x2 a, f32x2 b) {
  f32x2 d;
  asm("v_pk_add_f32 %0, %1, %2" : "=v"(d) : "v"(a), "v"(b));
  return d;
}
__device__ __forceinline__ f32x2 pk_mul(f32x2 a, f32x2 b) {
  f32x2 d;
  asm("v_pk_mul_f32 %0, %1, %2" : "=v"(d) : "v"(a), "v"(b));
  return d;
}
__device__ __forceinline__ f32x2 pk_fma(f32x2 a, f32x2 b, f32x2 c) {
  f32x2 d;
  asm("v_pk_fma_f32 %0, %1, %2, %3" : "=v"(d) : "v"(a), "v"(b), "v"(c));
  return d;
}
__device__ __forceinline__ unsigned cvtpk_neg(float a, float b) {
  unsigned r;   // packs bf16(-a) | bf16(-b)<<16, RNE
  asm("v_cvt_pk_bf16_f32 %0, -%1, -%2" : "=v"(r) : "v"(a), "v"(b));
  return r;
}

// ---- kernel 1: A(f32) -> A_bf16, plus per-block partial sums of A^2 --------
__global__ __launch_bounds__(256) void prep_a(const float* __restrict__ A,
                                              unsigned short* __restrict__ Abf,
                                              float* __restrict__ partials) {
  int tid = threadIdx.x;
  int idx = (blockIdx.x * 256 + tid) * 4;          // 128 blocks * 1024 f32
  float4 v = *(const float4*)(A + idx);
  u16x4 o;
  o[0] = f2bf(v.x); o[1] = f2bf(v.y); o[2] = f2bf(v.z); o[3] = f2bf(v.w);
  *(u16x4*)(Abf + idx) = o;
  float p = v.x * v.x + v.y * v.y + v.z * v.z + v.w * v.w;
#pragma unroll
  for (int m = 32; m >= 1; m >>= 1) p += __shfl_xor(p, m, 64);
  __shared__ float red[4];
  if ((tid & 63) == 0) red[tid >> 6] = p;
  __syncthreads();
  if (tid == 0) partials[blockIdx.x] = red[0] + red[1] + red[2] + red[3];
}

// ---- kernel 2: M_bf16 = A A^T / L; L; momentum tables (-c_k, 1+c_k) --------
__global__ __launch_bounds__(256) void prep_m(const float* __restrict__ A,
                                              const float* __restrict__ partials,
                                              float* __restrict__ Lout,
                                              unsigned short* __restrict__ Mb,
                                              float* __restrict__ nct,
                                              float* __restrict__ cpt) {
  int tid = threadIdx.x;
  int k = blockIdx.x;
  int w = tid >> 6, l = tid & 63;
  __shared__ float ak[1024];
  *(float4*)(ak + tid * 4) = *(const float4*)(A + k * 1024 + tid * 4);
  float L = 0.f;
#pragma unroll 1
  for (int i = 0; i < 128; ++i) L += partials[i];  // fixed order: deterministic
  float invL = 1.0f / L;
  if (k == 0 && tid == 0) {
    Lout[0] = L;
    float t = 1.0f;
#pragma unroll 1
    for (int i = 0; i < NITER; ++i) {
      float tn = 0.5f * (1.0f + sqrtf(1.0f + 4.0f * t * t));
      float c = (t - 1.0f) / tn;
      nct[i] = -c;
      cpt[i] = 1.0f + c;
      t = tn;
    }
  }
  __syncthreads();
#pragma unroll 1
  for (int jj = 0; jj < 32; ++jj) {
    int j = w * 32 + jj;
    const float* aj = A + j * 1024;
    float p = 0.f;
#pragma unroll
    for (int q = 0; q < 4; ++q) {
      float4 x = *(const float4*)(aj + q * 256 + l * 4);
      float4 y = *(const float4*)(ak + q * 256 + l * 4);
      p += x.x * y.x + x.y * y.y + x.z * y.z + x.w * y.w;
    }
#pragma unroll
    for (int m = 32; m >= 1; m >>= 1) p += __shfl_xor(p, m, 64);
    if (l == 0) Mb[k * 128 + j] = f2bf(p * invL);
  }
}

// ---- kernel 3: FISTA, block = 4 waves x 32 samples (2 groups of 16) --------
// lane l: li=l&15 (sample-in-group), g=l>>4.  Wave w: codes [32w, 32w+32).
//   mfr[t][m] : A-frag of M, rows 32w+16t+li, k=32m+8g..+8   (t<2, m<4)
//   zf[m]     : B-frag, col(sample)=li, k(code)=32m+8g..+8
//   D[t]      : codes 32w+16t+4g+r (r<4), sample li
// LDS z bf16: [buf(2)][group(2)][16 samples][128 codes]; 16B chunks
// XOR-swizzled by sample (ushort = li*128 + ((chunk^li)*8) + within).
__global__ __launch_bounds__(256, 4) void fista(const float* __restrict__ X,
                                                const unsigned short* __restrict__ Abf,
                                                const unsigned short* __restrict__ Mb,
                                                const float* __restrict__ Lptr,
                                                const float* __restrict__ nct,
                                                const float* __restrict__ cpt,
                                                float* __restrict__ out) {
  int tid = threadIdx.x;
  int w = tid >> 6, l = tid & 63;
  int li = l & 15, g = l >> 4;
  int s0 = blockIdx.x * 32;

  __shared__ __align__(16) unsigned short zls[8192];  // 16 KB

  float L = Lptr[0];
  float invL = 1.0f / L;
  float thr = 0.2f / L;
  float nthr = -thr;

  // zero buf0, both groups (4096 ushorts): 16 ushorts per thread
  *(u32x4*)(zls + tid * 16) = u32x4{0u, 0u, 0u, 0u};
  *(u32x4*)(zls + tid * 16 + 8) = u32x4{0u, 0u, 0u, 0u};

  // ---- prologue: acc[gg][t] = Abf_rows . X^T (K=1024), X direct global ----
  f32x4 acc[2][2];
#pragma unroll
  for (int gg = 0; gg < 2; ++gg)
#pragma unroll
    for (int t = 0; t < 2; ++t) acc[gg][t] = f32x4{0.f, 0.f, 0.f, 0.f};

  const float* xA = X + (size_t)(s0 + li) * 1024 + 8 * g;
  const float* xB = xA + 16 * 1024;
  const unsigned short* arow = Abf + (size_t)(32 * w + li) * 1024 + 8 * g;
#pragma unroll 2
  for (int ks = 0; ks < 32; ++ks) {
    float4 a0 = *(const float4*)(xA + ks * 32);
    float4 a1 = *(const float4*)(xA + ks * 32 + 4);
    float4 b0 = *(const float4*)(xB + ks * 32);
    float4 b1 = *(const float4*)(xB + ks * 32 + 4);
    bf16x8 xfA, xfB;
    xfA[0] = (__bf16)a0.x; xfA[1] = (__bf16)a0.y; xfA[2] = (__bf16)a0.z; xfA[3] = (__bf16)a0.w;
    xfA[4] = (__bf16)a1.x; xfA[5] = (__bf16)a1.y; xfA[6] = (__bf16)a1.z; xfA[7] = (__bf16)a1.w;
    xfB[0] = (__bf16)b0.x; xfB[1] = (__bf16)b0.y; xfB[2] = (__bf16)b0.z; xfB[3] = (__bf16)b0.w;
    xfB[4] = (__bf16)b1.x; xfB[5] = (__bf16)b1.y; xfB[6] = (__bf16)b1.z; xfB[7] = (__bf16)b1.w;
#pragma unroll
    for (int t = 0; t < 2; ++t) {
      bf16x8 af = *(const bf16x8*)(arow + (size_t)t * 16384 + ks * 32);
      acc[0][t] = __builtin_amdgcn_mfma_f32_16x16x32_bf16(af, xfA, acc[0][t], 0, 0, 0);
      acc[1][t] = __builtin_amdgcn_mfma_f32_16x16x32_bf16(af, xfB, acc[1][t], 0, 0, 0);
    }
  }

  // Bn = -B as f32x2 halves; negated state nzr=-z, nxr=-x (f32)
  f32x2 Bn[2][2][2], nzr[2][2][2], nxr[2][2][2];
  float niv = -invL;
#pragma unroll
  for (int gg = 0; gg < 2; ++gg)
#pragma unroll
    for (int t = 0; t < 2; ++t) {
      Bn[gg][t][0] = f32x2{acc[gg][t][0] * niv, acc[gg][t][1] * niv};
      Bn[gg][t][1] = f32x2{acc[gg][t][2] * niv, acc[gg][t][3] * niv};
      nzr[gg][t][0] = f32x2{0.f, 0.f}; nzr[gg][t][1] = f32x2{0.f, 0.f};
      nxr[gg][t][0] = f32x2{0.f, 0.f}; nxr[gg][t][1] = f32x2{0.f, 0.f};
    }

  // M fragments (32 VGPRs), loaded after prologue
  bf16x8 mfr[2][4];
#pragma unroll
  for (int t = 0; t < 2; ++t)
#pragma unroll
    for (int m = 0; m < 4; ++m)
      mfr[t][m] = *(const bf16x8*)(Mb + (32 * w + 16 * t + li) * 128 + 32 * m + 8 * g);

  // LDS offsets (ushort units), group/buf strides folded as constants
  int roff[4], woff[2];
#pragma unroll
  for (int m = 0; m < 4; ++m) roff[m] = li * 128 + (((4 * m + g) ^ li) * 8);
#pragma unroll
  for (int t = 0; t < 2; ++t)
    woff[t] = li * 128 + (((4 * w + 2 * t + (g >> 1)) ^ li) * 8) + (g & 1) * 4;

  __syncthreads();   // buf0 zeroed

  // one momentum iteration: reads buf RD (both groups), writes buf WR
  auto body = [&](const int RD, const int WR, const int it) {
    float c_ = nct[it];    // -c_k (uniform scalar load)
    float cp_ = cpt[it];   // 1+c_k
    f32x2 ncc = f32x2{c_, c_};
    f32x2 cpp = f32x2{cp_, cp_};

    bf16x8 zfA[4];
#pragma unroll
    for (int m = 0; m < 4; ++m) zfA[m] = *(const bf16x8*)(zls + RD + roff[m]);

    f32x4 dA[2];
#pragma unroll
    for (int t = 0; t < 2; ++t) {
      f32x2 dlo = pk_add(Bn[0][t][0], nzr[0][t][0]);   // C = -B - z
      f32x2 dhi = pk_add(Bn[0][t][1], nzr[0][t][1]);
      f32x4 d = f32x4{dlo[0], dlo[1], dhi[0], dhi[1]};
      d = __builtin_amdgcn_mfma_f32_16x16x32_bf16(mfr[t][0], zfA[0], d, 0, 0, 0);
      d = __builtin_amdgcn_mfma_f32_16x16x32_bf16(mfr[t][1], zfA[1], d, 0, 0, 0);
      d = __builtin_amdgcn_mfma_f32_16x16x32_bf16(mfr[t][2], zfA[2], d, 0, 0, 0);
      d = __builtin_amdgcn_mfma_f32_16x16x32_bf16(mfr[t][3], zfA[3], d, 0, 0, 0);
      dA[t] = d;                                       // D = zM - z - B
    }

    bf16x8 zfB[4];
#pragma unroll
    for (int m = 0; m < 4; ++m) zfB[m] = *(const bf16x8*)(zls + RD + 2048 + roff[m]);

#pragma unroll
    for (int t = 0; t < 2; ++t) {                      // elementwise, group 0
      f32x4 d = dA[t];
      float nx0 = d[0] - med3(d[0], nthr, thr);        // nx = -x_new
      float nx1 = d[1] - med3(d[1], nthr, thr);
      float nx2 = d[2] - med3(d[2], nthr, thr);
      float nx3 = d[3] - med3(d[3], nthr, thr);
      f32x2 nx01 = f32x2{nx0, nx1}, nx23 = f32x2{nx2, nx3};
      f32x2 z01 = pk_fma(nx01, cpp, pk_mul(nxr[0][t][0], ncc));  // nz'
      f32x2 z23 = pk_fma(nx23, cpp, pk_mul(nxr[0][t][1], ncc));
      nxr[0][t][0] = nx01; nxr[0][t][1] = nx23;
      nzr[0][t][0] = z01;  nzr[0][t][1] = z23;
      u32x2 pv = u32x2{cvtpk_neg(z01[0], z01[1]), cvtpk_neg(z23[0], z23[1])};
      *(u32x2*)(zls + WR + woff[t]) = pv;              // z (positive) bf16
    }

#pragma unroll
    for (int t = 0; t < 2; ++t) {                      // group 1 matvec
      f32x2 dlo = pk_add(Bn[1][t][0], nzr[1][t][0]);
      f32x2 dhi = pk_add(Bn[1][t][1], nzr[1][t][1]);
      f32x4 d = f32x4{dlo[0], dlo[1], dhi[0], dhi[1]};
      d = __builtin_amdgcn_mfma_f32_16x16x32_bf16(mfr[t][0], zfB[0], d, 0, 0, 0);
      d = __builtin_amdgcn_mfma_f32_16x16x32_bf16(mfr[t][1], zfB[1], d, 0, 0, 0);
      d = __builtin_amdgcn_mfma_f32_16x16x32_bf16(mfr[t][2], zfB[2], d, 0, 0, 0);
      d = __builtin_amdgcn_mfma_f32_16x16x32_bf16(mfr[t][3], zfB[3], d, 0, 0, 0);
      float nx0 = d[0] - med3(d[0], nthr, thr);
      float nx1 = d[1] - med3(d[1], nthr, thr);
      float nx2 = d[2] - med3(d[2], nthr, thr);
      float nx3 = d[3] - med3(d[3], nthr, thr);
      f32x2 nx01 = f32x2{nx0, nx1}, nx23 = f32x2{nx2, nx3};
      f32x2 z01 = pk_fma(nx01, cpp, pk_mul(nxr[1][t][0], ncc));
      f32x2 z23 = pk_fma(nx23, cpp, pk_mul(nxr[1][t][1], ncc));
      nxr[1][t][0] = nx01; nxr[1][t][1] = nx23;
      nzr[1][t][0] = z01;  nzr[1][t][1] = z23;
      u32x2 pv = u32x2{cvtpk_neg(z01[0], z01[1]), cvtpk_neg(z23[0], z23[1])};
      *(u32x2*)(zls + WR + 2048 + woff[t]) = pv;
    }
    __syncthreads();
  };

#pragma unroll 1
  for (int u = 0; u < 39; ++u) {     // iters 0..77
    body(0, 4096, 2 * u);
    body(4096, 0, 2 * u + 1);
  }
  body(0, 4096, 78);                 // iter 78 -> z_79 in buf1

  // ---- final (80th) step: x in f32, store directly (reads buf1) ----
#pragma unroll
  for (int gg = 0; gg < 2; ++gg) {
    bf16x8 zf[4];
#pragma unroll
    for (int m = 0; m < 4; ++m)
      zf[m] = *(const bf16x8*)(zls + 4096 + 2048 * gg + roff[m]);
#pragma unroll
    for (int t = 0; t < 2; ++t) {
      f32x2 dlo = pk_add(Bn[gg][t][0], nzr[gg][t][0]);
      f32x2 dhi = pk_add(Bn[gg][t][1], nzr[gg][t][1]);
      f32x4 d = f32x4{dlo[0], dlo[1], dhi[0], dhi[1]};
      d = __builtin_amdgcn_mfma_f32_16x16x32_bf16(mfr[t][0], zf[0], d, 0, 0, 0);
      d = __builtin_amdgcn_mfma_f32_16x16x32_bf16(mfr[t][1], zf[1], d, 0, 0, 0);
      d = __builtin_amdgcn_mfma_f32_16x16x32_bf16(mfr[t][2], zf[2], d, 0, 0, 0);
      d = __builtin_amdgcn_mfma_f32_16x16x32_bf16(mfr[t][3], zf[3], d, 0, 0, 0);
      f32x4 xn;
#pragma unroll
      for (int r = 0; r < 4; ++r) {
        float dd = d[r];
        xn[r] = med3(dd, nthr, thr) - dd;   // x = soft(-dd)
      }
      *(f32x4*)(out + (size_t)(s0 + 16 * gg + li) * 128 + 32 * w + 16 * t + 4 * g) = xn;
    }
  }
}

extern "C" void kernel_launch(void* const* d_in, const int* in_sizes, int n_in,
                              void* d_out, int out_size, void* d_ws, size_t ws_size,
                              hipStream_t stream) {
  const float* X = (const float*)d_in[0];          // 32768 x 1024 f32
  const float* A = (const float*)d_in[1];          // 128 x 1024 f32
  float* out = (float*)d_out;                      // 32768 x 128 f32

  float* partials      = (float*)d_ws;                                   // 128 f32
  float* Lout          = (float*)((char*)d_ws + 512);                    // 1 f32
  unsigned short* Abf  = (unsigned short*)((char*)d_ws + 528);           // 256 KB
  unsigned short* Mb   = (unsigned short*)((char*)d_ws + 528 + 262144);  // 32 KB
  float* nct           = (float*)((char*)d_ws + 528 + 262144 + 32768);   // 96 f32
  float* cpt           = (float*)((char*)d_ws + 528 + 262144 + 32768 + 384);

  prep_a<<<128, 256, 0, stream>>>(A, Abf, partials);
  prep_m<<<128, 256, 0, stream>>>(A, partials, Lout, Mb, nct, cpt);
  fista<<<1024, 256, 0, stream>>>(X, Abf, Mb, Lout, nct, cpt, out);
}

// Round 7
// 176.841 us; speedup vs baseline: 1.3278x; 1.0451x over previous
//
#include <hip/hip_runtime.h>

// ---------------------------------------------------------------------------
// FISTA sparse coding:
//   L = ||A||_F^2 ; M = A A^T / L (128x128 bf16) ; B = X A^T / L
//   Block = 512 threads (8 waves) owns 16 samples; wave w owns codes
//   [16w, 16w+16)  ->  per-wave state ~64 VGPR, no AGPR traffic, 7-8
//   independent wave-streams per SIMD.
//   Prologue stages the X-tile (16x1024) once in LDS as bf16 (read by all 8
//   waves as MFMA B-frags) -> X is fetched from HBM exactly once.
//   z bf16 in LDS double-buffer (reusing the stage region), 1 barrier/iter.
//   Negated f32 register state (nz=-z, nx=-x): packed VOP3P + med3 + cvt_pk.
//   Momentum coefficients precomputed in prep_m.  Last iteration peeled.
// ---------------------------------------------------------------------------

typedef __attribute__((ext_vector_type(8))) __bf16 bf16x8;
typedef __attribute__((ext_vector_type(4))) float f32x4;
typedef __attribute__((ext_vector_type(2))) float f32x2;
typedef __attribute__((ext_vector_type(4))) unsigned short u16x4;
typedef __attribute__((ext_vector_type(2))) unsigned int u32x2;
typedef __attribute__((ext_vector_type(4))) unsigned int u32x4;

#define NITER 80

__device__ __forceinline__ unsigned short f2bf(float f) {
  unsigned int u = __builtin_bit_cast(unsigned int, f);
  u += 0x7FFFu + ((u >> 16) & 1u);   // RNE
  return (unsigned short)(u >> 16);
}
__device__ __forceinline__ float med3(float a, float b, float c) {
  float r;
  asm("v_med3_f32 %0, %1, %2, %3" : "=v"(r) : "v"(a), "v"(b), "v"(c));
  return r;
}
__device__ __forceinline__ f32x2 pk_add(f32x2 a, f32x2 b) {
  f32x2 d;
  asm("v_pk_add_f32 %0, %1, %2" : "=v"(d) : "v"(a), "v"(b));
  return d;
}
__device__ __forceinline__ f32x2 pk_mul(f32x2 a, f32x2 b) {
  f32x2 d;
  asm("v_pk_mul_f32 %0, %1, %2" : "=v"(d) : "v"(a), "v"(b));
  return d;
}
__device__ __forceinline__ f32x2 pk_fma(f32x2 a, f32x2 b, f32x2 c) {
  f32x2 d;
  asm("v_pk_fma_f32 %0, %1, %2, %3" : "=v"(d) : "v"(a), "v"(b), "v"(c));
  return d;
}
__device__ __forceinline__ unsigned cvtpk(float a, float b) {
  unsigned r;   // bf16(a) | bf16(b)<<16, RNE
  asm("v_cvt_pk_bf16_f32 %0, %1, %2" : "=v"(r) : "v"(a), "v"(b));
  return r;
}
__device__ __forceinline__ unsigned cvtpk_neg(float a, float b) {
  unsigned r;   // bf16(-a) | bf16(-b)<<16, RNE
  asm("v_cvt_pk_bf16_f32 %0, -%1, -%2" : "=v"(r) : "v"(a), "v"(b));
  return r;
}

// ---- kernel 1: A(f32) -> A_bf16, plus per-block partial sums of A^2 --------
__global__ __launch_bounds__(256) void prep_a(const float* __restrict__ A,
                                              unsigned short* __restrict__ Abf,
                                              float* __restrict__ partials) {
  int tid = threadIdx.x;
  int idx = (blockIdx.x * 256 + tid) * 4;          // 128 blocks * 1024 f32
  float4 v = *(const float4*)(A + idx);
  u16x4 o;
  o[0] = f2bf(v.x); o[1] = f2bf(v.y); o[2] = f2bf(v.z); o[3] = f2bf(v.w);
  *(u16x4*)(Abf + idx) = o;
  float p = v.x * v.x + v.y * v.y + v.z * v.z + v.w * v.w;
#pragma unroll
  for (int m = 32; m >= 1; m >>= 1) p += __shfl_xor(p, m, 64);
  __shared__ float red[4];
  if ((tid & 63) == 0) red[tid >> 6] = p;
  __syncthreads();
  if (tid == 0) partials[blockIdx.x] = red[0] + red[1] + red[2] + red[3];
}

// ---- kernel 2: M_bf16 = A A^T / L; L; momentum tables (-c_k, 1+c_k) --------
__global__ __launch_bounds__(256) void prep_m(const float* __restrict__ A,
                                              const float* __restrict__ partials,
                                              float* __restrict__ Lout,
                                              unsigned short* __restrict__ Mb,
                                              float* __restrict__ nct,
                                              float* __restrict__ cpt) {
  int tid = threadIdx.x;
  int k = blockIdx.x;
  int w = tid >> 6, l = tid & 63;
  __shared__ float ak[1024];
  *(float4*)(ak + tid * 4) = *(const float4*)(A + k * 1024 + tid * 4);
  float L = 0.f;
#pragma unroll 1
  for (int i = 0; i < 128; ++i) L += partials[i];  // fixed order: deterministic
  float invL = 1.0f / L;
  if (k == 0 && tid == 0) {
    Lout[0] = L;
    float t = 1.0f;
#pragma unroll 1
    for (int i = 0; i < NITER; ++i) {
      float tn = 0.5f * (1.0f + sqrtf(1.0f + 4.0f * t * t));
      float c = (t - 1.0f) / tn;
      nct[i] = -c;
      cpt[i] = 1.0f + c;
      t = tn;
    }
  }
  __syncthreads();
#pragma unroll 1
  for (int jj = 0; jj < 32; ++jj) {
    int j = w * 32 + jj;
    const float* aj = A + j * 1024;
    float p = 0.f;
#pragma unroll
    for (int q = 0; q < 4; ++q) {
      float4 x = *(const float4*)(aj + q * 256 + l * 4);
      float4 y = *(const float4*)(ak + q * 256 + l * 4);
      p += x.x * y.x + x.y * y.y + x.z * y.z + x.w * y.w;
    }
#pragma unroll
    for (int m = 32; m >= 1; m >>= 1) p += __shfl_xor(p, m, 64);
    if (l == 0) Mb[k * 128 + j] = f2bf(p * invL);
  }
}

// ---- kernel 3: FISTA, block = 8 waves x 16 samples; wave w: 16 codes -------
// lane l: li=l&15 (sample), g=l>>4.
//   mfr[m] : A-frag of M, rows 16w+li, k=32m+8g..+8          (m<4)
//   zf[m]  : B-frag, col(sample)=li, k(code)=32m+8g..+8      (all 128 codes)
//   d      : codes 16w+4g+r (r<4), sample li
// LDS: ushort lds[16384] (32 KB).
//   Prologue: X-stage [16 rows][128 chunks of 8 bf16], chunk^=(row&7).
//   Iterations: z dbuf at [0,2048) and [2048,4096) ushorts,
//   [16 samples][16 chunks], chunk^=sample (li).
__global__ __launch_bounds__(512, 6) void fista(const float* __restrict__ X,
                                                const unsigned short* __restrict__ Abf,
                                                const unsigned short* __restrict__ Mb,
                                                const float* __restrict__ Lptr,
                                                const float* __restrict__ nct,
                                                const float* __restrict__ cpt,
                                                float* __restrict__ out) {
  int tid = threadIdx.x;
  int w = tid >> 6, l = tid & 63;
  int li = l & 15, g = l >> 4;
  int s0 = blockIdx.x * 16;

  __shared__ __align__(16) unsigned short lds[16384];  // 32 KB

  float L = Lptr[0];
  float invL = 1.0f / L;
  float thr = 0.2f / L;
  float nthr = -thr;

  // ---- stage X tile (16 x 1024 f32 -> bf16) into LDS, swizzled ----
  {
    int r = tid >> 5, t32 = tid & 31;           // row, 32 threads per row
    const float* xsrc = X + (size_t)(s0 + r) * 1024;
#pragma unroll
    for (int i = 0; i < 4; ++i) {
      int c = t32 + 32 * i;                     // chunk (8 bf16), k = 8c
      float4 v0 = *(const float4*)(xsrc + 8 * c);
      float4 v1 = *(const float4*)(xsrc + 8 * c + 4);
      u32x4 pk;
      pk[0] = cvtpk(v0.x, v0.y); pk[1] = cvtpk(v0.z, v0.w);
      pk[2] = cvtpk(v1.x, v1.y); pk[3] = cvtpk(v1.z, v1.w);
      *(u32x4*)(lds + r * 1024 + ((c ^ (r & 7)) * 8)) = pk;
    }
  }
  __syncthreads();

  // ---- prologue: acc = Abf_rows(16w+li) . X^T (K=1024), X from LDS ----
  f32x4 acc = f32x4{0.f, 0.f, 0.f, 0.f};
  const unsigned short* arow = Abf + (size_t)(16 * w + li) * 1024 + 8 * g;
  int lsw = li & 7;
#pragma unroll 8
  for (int ks = 0; ks < 32; ++ks) {
    bf16x8 xf = *(const bf16x8*)(lds + li * 1024 + (((4 * ks + g) ^ lsw) * 8));
    bf16x8 af = *(const bf16x8*)(arow + ks * 32);
    acc = __builtin_amdgcn_mfma_f32_16x16x32_bf16(af, xf, acc, 0, 0, 0);
  }
  __syncthreads();   // all X-stage reads done before z-zero overwrites

  float niv = -invL;
  f32x2 Bn0 = f32x2{acc[0] * niv, acc[1] * niv};   // Bn = -B
  f32x2 Bn1 = f32x2{acc[2] * niv, acc[3] * niv};
  f32x2 nz0 = f32x2{0.f, 0.f}, nz1 = f32x2{0.f, 0.f};
  f32x2 nx0 = f32x2{0.f, 0.f}, nx1 = f32x2{0.f, 0.f};

  // M fragments (16 VGPRs)
  bf16x8 mfr[4];
#pragma unroll
  for (int m = 0; m < 4; ++m)
    mfr[m] = *(const bf16x8*)(Mb + (16 * w + li) * 128 + 32 * m + 8 * g);

  // zero z buffer 0: 4096 ushorts over 512 threads = 8 ushorts each
  *(u32x4*)(lds + tid * 8) = u32x4{0u, 0u, 0u, 0u};
  __syncthreads();

  // LDS offsets (ushort units)
  int roff[4];
#pragma unroll
  for (int m = 0; m < 4; ++m) roff[m] = li * 128 + (((4 * m + g) ^ li) * 8);
  int woff = li * 128 + (((2 * w + (g >> 1)) ^ li) * 8) + (g & 1) * 4;

  // one momentum iteration: reads buf RD, writes buf WR (compile-time offs)
  auto body = [&](const int RD, const int WR, const int it) {
    float c_ = nct[it];    // -c_k (uniform scalar load)
    float cp_ = cpt[it];   // 1+c_k
    f32x2 ncc = f32x2{c_, c_};
    f32x2 cpp = f32x2{cp_, cp_};

    bf16x8 zf[4];
#pragma unroll
    for (int m = 0; m < 4; ++m) zf[m] = *(const bf16x8*)(lds + RD + roff[m]);

    f32x2 dlo = pk_add(Bn0, nz0);               // C = -B - z
    f32x2 dhi = pk_add(Bn1, nz1);
    f32x4 d = f32x4{dlo[0], dlo[1], dhi[0], dhi[1]};
    d = __builtin_amdgcn_mfma_f32_16x16x32_bf16(mfr[0], zf[0], d, 0, 0, 0);
    d = __builtin_amdgcn_mfma_f32_16x16x32_bf16(mfr[1], zf[1], d, 0, 0, 0);
    d = __builtin_amdgcn_mfma_f32_16x16x32_bf16(mfr[2], zf[2], d, 0, 0, 0);
    d = __builtin_amdgcn_mfma_f32_16x16x32_bf16(mfr[3], zf[3], d, 0, 0, 0);
    // D = zM - z - B  =>  zpre = -D ;  nx = -x = d - clamp(d)
    float a0 = d[0] - med3(d[0], nthr, thr);
    float a1 = d[1] - med3(d[1], nthr, thr);
    float a2 = d[2] - med3(d[2], nthr, thr);
    float a3 = d[3] - med3(d[3], nthr, thr);
    f32x2 n01 = f32x2{a0, a1}, n23 = f32x2{a2, a3};
    f32x2 z01 = pk_fma(n01, cpp, pk_mul(nx0, ncc));   // nz' = cp*nx - c*nx_old
    f32x2 z23 = pk_fma(n23, cpp, pk_mul(nx1, ncc));
    nx0 = n01; nx1 = n23;
    nz0 = z01; nz1 = z23;
    u32x2 pv = u32x2{cvtpk_neg(z01[0], z01[1]), cvtpk_neg(z23[0], z23[1])};
    *(u32x2*)(lds + WR + woff) = pv;            // z (positive) bf16
    __syncthreads();
  };

#pragma unroll 1
  for (int u = 0; u < 39; ++u) {     // iters 0..77
    body(0, 2048, 2 * u);
    body(2048, 0, 2 * u + 1);
  }
  body(0, 2048, 78);                 // iter 78 -> z_79 in buf1

  // ---- final (80th) step: x in f32, store directly (reads buf1) ----
  {
    bf16x8 zf[4];
#pragma unroll
    for (int m = 0; m < 4; ++m) zf[m] = *(const bf16x8*)(lds + 2048 + roff[m]);
    f32x2 dlo = pk_add(Bn0, nz0);
    f32x2 dhi = pk_add(Bn1, nz1);
    f32x4 d = f32x4{dlo[0], dlo[1], dhi[0], dhi[1]};
    d = __builtin_amdgcn_mfma_f32_16x16x32_bf16(mfr[0], zf[0], d, 0, 0, 0);
    d = __builtin_amdgcn_mfma_f32_16x16x32_bf16(mfr[1], zf[1], d, 0, 0, 0);
    d = __builtin_amdgcn_mfma_f32_16x16x32_bf16(mfr[2], zf[2], d, 0, 0, 0);
    d = __builtin_amdgcn_mfma_f32_16x16x32_bf16(mfr[3], zf[3], d, 0, 0, 0);
    f32x4 xn;
#pragma unroll
    for (int r = 0; r < 4; ++r) {
      float dd = d[r];
      xn[r] = med3(dd, nthr, thr) - dd;   // x = soft(-dd)
    }
    *(f32x4*)(out + (size_t)(s0 + li) * 128 + 16 * w + 4 * g) = xn;
  }
}

extern "C" void kernel_launch(void* const* d_in, const int* in_sizes, int n_in,
                              void* d_out, int out_size, void* d_ws, size_t ws_size,
                              hipStream_t stream) {
  const float* X = (const float*)d_in[0];          // 32768 x 1024 f32
  const float* A = (const float*)d_in[1];          // 128 x 1024 f32
  float* out = (float*)d_out;                      // 32768 x 128 f32

  float* partials      = (float*)d_ws;                                   // 128 f32
  float* Lout          = (float*)((char*)d_ws + 512);                    // 1 f32
  unsigned short* Abf  = (unsigned short*)((char*)d_ws + 528);           // 256 KB
  unsigned short* Mb   = (unsigned short*)((char*)d_ws + 528 + 262144);  // 32 KB
  float* nct           = (float*)((char*)d_ws + 528 + 262144 + 32768);   // 96 f32
  float* cpt           = (float*)((char*)d_ws + 528 + 262144 + 32768 + 384);

  prep_a<<<128, 256, 0, stream>>>(A, Abf, partials);
  prep_m<<<128, 256, 0, stream>>>(A, partials, Lout, Mb, nct, cpt);
  fista<<<2048, 512, 0, stream>>>(X, Abf, Mb, Lout, nct, cpt, out);
}